// Round 1
// baseline (2113.488 us; speedup 1.0000x reference)
//
#include <hip/hip_runtime.h>

#define B_   16
#define CI   64
#define CO   64
#define H_   256
#define W_   256

#define TILE     32   // spatial tile (both dims)
#define CI_CHUNK 8    // c_in staged per LDS pass
#define CO_T     16   // c_out per block
#define SROW     35   // 34 + 1 pad (breaks bank aliasing)

__global__ __launch_bounds__(256, 2) void conv3x3_tiled(
    const float* __restrict__ x, const float* __restrict__ wgt,
    const float* __restrict__ bias, float* __restrict__ out)
{
    __shared__ float s_in[CI_CHUNK][34][SROW];
    __shared__ float s_w[CI_CHUNK][9][CO_T];   // [ci][tap][co] -> float4-broadcastable

    const int t   = threadIdx.x;
    const int b   = blockIdx.z;
    const int co0 = blockIdx.y * CO_T;
    const int ty0 = (blockIdx.x >> 3) * TILE;
    const int tx0 = (blockIdx.x & 7) * TILE;

    const int px = t & 31;          // x within tile (32 lanes -> coalesced)
    const int py = (t >> 5) << 2;   // y base: 4 contiguous rows per thread

    float acc[CO_T][4];
    #pragma unroll
    for (int c = 0; c < CO_T; ++c)
        #pragma unroll
        for (int k = 0; k < 4; ++k) acc[c][k] = 0.f;

    for (int ci0 = 0; ci0 < CI; ci0 += CI_CHUNK) {
        if (ci0) __syncthreads();

        // ---- stage input chunk (with zero-filled halo) ----
        const float* xb = x + (size_t)(b * CI + ci0) * H_ * W_;
        for (int idx = t; idx < CI_CHUNK * 34 * 34; idx += 256) {
            int ci = idx / (34 * 34);
            int r  = idx - ci * (34 * 34);
            int iy = r / 34;
            int ix = r - iy * 34;
            int gy = ty0 + iy - 1;
            int gx = tx0 + ix - 1;
            float v = 0.f;
            if ((unsigned)gy < (unsigned)H_ && (unsigned)gx < (unsigned)W_)
                v = xb[(size_t)ci * (H_ * W_) + gy * W_ + gx];
            s_in[ci][iy][ix] = v;
        }
        // ---- stage weights ----
        for (int idx = t; idx < CI_CHUNK * 9 * CO_T; idx += 256) {
            int ci  = idx / (9 * CO_T);
            int r   = idx - ci * (9 * CO_T);
            int tap = r / CO_T;
            int co  = r - tap * CO_T;
            s_w[ci][tap][co] = wgt[((co0 + co) * CI + ci0 + ci) * 9 + tap];
        }
        __syncthreads();

        // ---- compute ----
        #pragma unroll 1
        for (int ci = 0; ci < CI_CHUNK; ++ci) {
            float in_reg[6][3];
            #pragma unroll
            for (int dy = 0; dy < 6; ++dy)
                #pragma unroll
                for (int dx = 0; dx < 3; ++dx)
                    in_reg[dy][dx] = s_in[ci][py + dy][px + dx];

            #pragma unroll
            for (int tap = 0; tap < 9; ++tap) {
                const int ky = tap / 3, kx = tap % 3;
                #pragma unroll
                for (int c4 = 0; c4 < CO_T / 4; ++c4) {
                    float4 wv = *(const float4*)&s_w[ci][tap][c4 * 4];
                    #pragma unroll
                    for (int k = 0; k < 4; ++k) {
                        float iv = in_reg[k + ky][kx];
                        acc[c4 * 4 + 0][k] += wv.x * iv;
                        acc[c4 * 4 + 1][k] += wv.y * iv;
                        acc[c4 * 4 + 2][k] += wv.z * iv;
                        acc[c4 * 4 + 3][k] += wv.w * iv;
                    }
                }
            }
        }
    }

    // ---- epilogue: coalesced stores, all outputs written ----
    #pragma unroll
    for (int c = 0; c < CO_T; ++c) {
        float bv = bias[co0 + c];
        size_t base = ((size_t)(b * CO + co0 + c) * H_ + (ty0 + py)) * W_ + tx0 + px;
        #pragma unroll
        for (int k = 0; k < 4; ++k)
            out[base + (size_t)k * W_] = acc[c][k] + bv;
    }
}

extern "C" void kernel_launch(void* const* d_in, const int* in_sizes, int n_in,
                              void* d_out, int out_size, void* d_ws, size_t ws_size,
                              hipStream_t stream) {
    const float* x    = (const float*)d_in[0];
    const float* wgt  = (const float*)d_in[1];
    const float* bias = (const float*)d_in[2];
    float* out = (float*)d_out;

    dim3 grid(64 /* 8x8 spatial */, CO / CO_T /* 4 */, B_ /* 16 */);
    dim3 block(256);
    conv3x3_tiled<<<grid, block, 0, stream>>>(x, wgt, bias, out);
}

// Round 2
// 751.776 us; speedup vs baseline: 2.8113x; 2.8113x over previous
//
#include <hip/hip_runtime.h>

#define HWX 65536u   // 256*256

typedef __attribute__((ext_vector_type(8)))  __bf16 bf16x8;
typedef __attribute__((ext_vector_type(16))) float  f32x16;

__device__ __forceinline__ unsigned f2bf(float f) {
    union { float f; unsigned u; } v; v.f = f;
    unsigned u = v.u;
    return (u + 0x7fffu + ((u >> 16) & 1u)) >> 16;   // RNE -> low 16 bits
}

// Block: 256 thr = 4 waves. Tile: 64 co x (8 rows x 32 cols). Persistent: 8 tiles/block.
// Wave: co-half = (wave&1)*32, row-quad = (wave>>1)*4.
// LDS input tile: cells [iy 0..9][ix 0..33] of 128B (64ci bf16), 16B chunks XOR-swizzled by ix&7.
__global__ __launch_bounds__(256, 2) void conv_mfma(
    const float* __restrict__ x, const float* __restrict__ wgt,
    const float* __restrict__ bias, float* __restrict__ out)
{
    __shared__ __align__(16) char s_in[10 * 34 * 128];   // 43520 B

    const int t    = threadIdx.x;
    const int l    = t & 63;
    const int wave = t >> 6;
    const int n    = l & 31;           // MFMA N/M lane index
    const int half = l >> 5;
    const int co0  = (wave & 1) * 32;
    const int wrow = (wave >> 1) * 4;

    // ---- preload A-frags (weights) once per block: A[m=n][k=half*8+j], ci=kc*16+half*8+j ----
    bf16x8 afrag[9][4];
    #pragma unroll
    for (int tap = 0; tap < 9; ++tap) {
        #pragma unroll
        for (int kc = 0; kc < 4; ++kc) {
            union { unsigned short s[8]; bf16x8 v; } u;
            #pragma unroll
            for (int j = 0; j < 8; ++j) {
                int ci = kc * 16 + half * 8 + j;
                float f = wgt[(unsigned)((co0 + n) * 64 + ci) * 9u + (unsigned)tap];
                u.s[j] = (unsigned short)f2bf(f);
            }
            afrag[tap][kc] = u.v;
        }
    }

    // ---- B-frag LDS byte offsets, iy folded into the ds_read immediate ----
    unsigned boff[4][3];
    #pragma unroll
    for (int kc = 0; kc < 4; ++kc)
        #pragma unroll
        for (int dx = 0; dx < 3; ++dx) {
            int ix = n + dx;
            int chunk = (kc * 2 + half) ^ (ix & 7);
            boff[kc][dx] = (unsigned)(ix * 128 + chunk * 16);
        }

    for (int i = 0; i < 8; ++i) {
        const int tile = (int)blockIdx.x + i * 512;
        const int b    = tile >> 8;
        const int rem  = tile & 255;
        const int y0   = (rem >> 3) * 8;
        const int x0   = (rem & 7) * 32;

        // ---- stage input tile: fp32 -> bf16, coalesced in x ----
        const unsigned xbase = (unsigned)b * 64u * HWX;
        #pragma unroll 4
        for (int it = 0; it < 43; ++it) {
            int flat = t + it * 256;                 // [cp 0..31][iy 0..9][ix 0..33]
            int ix   = flat % 34;
            int tmp  = flat / 34;
            int iy   = tmp % 10;
            int cp   = tmp / 10;
            int gy = y0 + iy - 1, gx = x0 + ix - 1;
            bool ok  = (flat < 10880);
            bool inb = ok && ((unsigned)gy < 256u) && ((unsigned)gx < 256u);
            unsigned ga = xbase + (unsigned)(cp * 2) * HWX + (unsigned)gy * 256u + (unsigned)gx;
            float f0 = inb ? x[ga] : 0.f;
            float f1 = inb ? x[ga + HWX] : 0.f;
            if (ok) {
                unsigned off = (unsigned)((iy * 34 + ix) * 128)
                             + (unsigned)((((cp >> 2) ^ (ix & 7)) << 4) | ((cp & 3) << 2));
                *(unsigned*)(s_in + off) = f2bf(f0) | (f2bf(f1) << 16);
            }
        }
        __syncthreads();

        // ---- compute: 144 x (ds_read_b128 + mfma_32x32x16_bf16) per wave ----
        f32x16 acc[4];
        #pragma unroll
        for (int r = 0; r < 4; ++r) acc[r] = (f32x16)0.0f;

        #pragma unroll
        for (int dy = 0; dy < 3; ++dy)
          #pragma unroll
          for (int dx = 0; dx < 3; ++dx)
            #pragma unroll
            for (int kc = 0; kc < 4; ++kc)
              #pragma unroll
              for (int r = 0; r < 4; ++r) {
                  const int iy = wrow + r + dy;
                  const bf16x8 bfrag =
                      *(const bf16x8*)(s_in + iy * 34 * 128 + boff[kc][dx]);
                  acc[r] = __builtin_amdgcn_mfma_f32_32x32x16_bf16(
                      afrag[dy * 3 + dx][kc], bfrag, acc[r], 0, 0, 0);
              }
        __syncthreads();   // LDS reads done before next tile's staging

        // ---- epilogue: bias + coalesced dword stores ----
        float bv[16];
        #pragma unroll
        for (int reg = 0; reg < 16; ++reg)
            bv[reg] = bias[co0 + (reg & 3) + 8 * (reg >> 2) + 4 * half];

        const unsigned obase = (unsigned)b * 64u * HWX + (unsigned)x0 + (unsigned)n;
        #pragma unroll
        for (int r = 0; r < 4; ++r) {
            const unsigned Y = (unsigned)(y0 + wrow + r);
            #pragma unroll
            for (int reg = 0; reg < 16; ++reg) {
                const int row = (reg & 3) + 8 * (reg >> 2) + 4 * half;
                const int co  = co0 + row;
                out[obase + (unsigned)co * HWX + Y * 256u] = acc[r][reg] + bv[reg];
            }
        }
    }
}

extern "C" void kernel_launch(void* const* d_in, const int* in_sizes, int n_in,
                              void* d_out, int out_size, void* d_ws, size_t ws_size,
                              hipStream_t stream) {
    const float* x    = (const float*)d_in[0];
    const float* wgt  = (const float*)d_in[1];
    const float* bias = (const float*)d_in[2];
    float* out = (float*)d_out;

    conv_mfma<<<dim3(512), dim3(256), 0, stream>>>(x, wgt, bias, out);
}

// Round 3
// 636.057 us; speedup vs baseline: 3.3228x; 1.1819x over previous
//
#include <hip/hip_runtime.h>
#include <hip/hip_bf16.h>

#define HWX 65536u    // 256*256
#define ROWS 18       // 16-row tile + 2 halo
#define RCELLS 34     // 32 cols + 2 halo; cell = 128 B (64 ci bf16), 16B chunks XOR-swizzled by ix&7

typedef __attribute__((ext_vector_type(8)))  __bf16 bf16x8;
typedef __attribute__((ext_vector_type(16))) float  f32x16;

__device__ __forceinline__ unsigned pk2(float lo, float hi) {
    __hip_bfloat162 p = __float22bfloat162_rn(make_float2(lo, hi));  // v_cvt_pk_bf16_f32
    union { __hip_bfloat162 b; unsigned u; } v; v.b = p; return v.u;
}

// Repack weights fp32 [co][ci][tap] -> bf16 A-frag table [(tap*4+kc)*2+h][co][j8] in d_ws.
__global__ void prep_weights(const float* __restrict__ wgt,
                             unsigned short* __restrict__ wsA) {
    int idx = blockIdx.x * 256 + threadIdx.x;
    if (idx >= 9 * 64 * 64) return;
    int j    = idx & 7;
    int co   = (idx >> 3) & 63;
    int rest = idx >> 9;                   // (tap*4+kc)*2 + h
    int h = rest & 1, kc = (rest >> 1) & 3, tap = rest >> 3;
    int ci = kc * 16 + h * 8 + j;
    __hip_bfloat16 b = __float2bfloat16(wgt[(co * 64 + ci) * 9 + tap]);
    union { __hip_bfloat16 b; unsigned short s; } v; v.b = b;
    wsA[idx] = v.s;
}

// Block: 512 thr = 8 waves; tile 64co x (16 rows x 32 cols); 4 x-adjacent tiles per block.
// Wave: co-half = (wave&1)*32, row-quad = (wave>>1)*4. acc = 4 x f32x16 (64 VGPR).
__global__ __launch_bounds__(512, 4) void conv_mfma(
    const float* __restrict__ x, const unsigned short* __restrict__ wsA_in,
    const float* __restrict__ bias, float* __restrict__ out)
{
    __shared__ __align__(16) char s_in[ROWS * RCELLS * 128];   // 78336 B -> 2 blocks/CU

    const int t    = threadIdx.x;
    const int l    = t & 63;
    const int wave = t >> 6;
    const int n    = l & 31;
    const int h    = l >> 5;
    const int co0  = (wave & 1) * 32;
    const int wrow = (wave >> 1) * 4;

    const int bid   = (int)blockIdx.x;     // 512 blocks
    const int xh    = bid & 1;
    const int strip = (bid >> 1) & 15;
    const int b     = bid >> 5;
    const int y0    = strip * 16;

    const int cp  = t >> 4;    // ci pair 0..31
    const int ixp = t & 15;    // column pair

    const float* xp0 = x + (size_t)(b * 64 + cp * 2) * HWX;

    for (int i = 0; i < 4; ++i) {
        const int x0 = (xh * 4 + i) * 32;

        // ---- stage interior: aligned full-line float2 runs, pack 2 ci -> 1 dword ----
        #pragma unroll 6
        for (int iy = 0; iy < ROWS; ++iy) {
            const int gy = y0 + iy - 1;
            float2 a = make_float2(0.f, 0.f), c = make_float2(0.f, 0.f);
            if ((unsigned)gy < 256u) {
                const float* p = xp0 + (unsigned)gy * 256u + (unsigned)(x0 + ixp * 2);
                a = *(const float2*)p;
                c = *(const float2*)(p + HWX);
            }
            const int ix0 = ixp * 2 + 1;                      // interior cells 1..32
            unsigned base = (unsigned)((iy * RCELLS + ix0) * 128);
            unsigned o0 = base + ((((cp >> 2) ^ (ix0 & 7)) << 4) | ((cp & 3) << 2));
            unsigned o1 = base + 128 + ((((cp >> 2) ^ ((ix0 + 1) & 7)) << 4) | ((cp & 3) << 2));
            *(unsigned*)(s_in + o0) = pk2(a.x, c.x);
            *(unsigned*)(s_in + o1) = pk2(a.y, c.y);
        }
        // ---- stage halo columns: cells ix=0 (gx=x0-1) and ix=33 (gx=x0+32) ----
        #pragma unroll
        for (int it = 0; it < 3; ++it) {
            int id = t + it * 512;
            if (id < 1152) {
                int col = (id >= 576) ? 1 : 0;
                int r   = id - col * 576;
                int iy  = r >> 5;
                int cq  = r & 31;
                int gx  = col ? x0 + 32 : x0 - 1;
                int gy  = y0 + iy - 1;
                float f0 = 0.f, f1 = 0.f;
                if (((unsigned)gy < 256u) && ((unsigned)gx < 256u)) {
                    const float* q = x + (size_t)(b * 64 + cq * 2) * HWX
                                   + (unsigned)gy * 256u + (unsigned)gx;
                    f0 = q[0]; f1 = q[HWX];
                }
                int ix = col ? 33 : 0;
                unsigned off = (unsigned)((iy * RCELLS + ix) * 128)
                             + ((((cq >> 2) ^ (ix & 7)) << 4) | ((cq & 3) << 2));
                *(unsigned*)(s_in + off) = pk2(f0, f1);
            }
        }
        __syncthreads();

        // ---- compute: 72 ds_read_b128 feed 144 MFMA (B-frag reused across dy) ----
        const unsigned short* wp = wsA_in;
        asm volatile("" : "+s"(wp));    // defeat LICM: keep only 3 afrags (12 VGPR) live

        f32x16 acc[4];
        #pragma unroll
        for (int r = 0; r < 4; ++r) acc[r] = (f32x16)0.0f;

        #pragma unroll
        for (int dx = 0; dx < 3; ++dx) {
            #pragma unroll
            for (int kc = 0; kc < 4; ++kc) {
                bf16x8 af[3];
                #pragma unroll
                for (int dy = 0; dy < 3; ++dy) {
                    const int tap = dy * 3 + dx;
                    af[dy] = *(const bf16x8*)(wp +
                        ((((tap * 4 + kc) * 2 + h) * 64 + co0 + n) * 8));
                }
                #pragma unroll
                for (int iyo = 0; iyo < 6; ++iyo) {
                    const int iy = wrow + iyo;
                    const int ix = n + dx;
                    const bf16x8 bf = *(const bf16x8*)(s_in
                        + (iy * RCELLS + ix) * 128 + (((kc * 2 + h) ^ (ix & 7)) << 4));
                    #pragma unroll
                    for (int dy = 0; dy < 3; ++dy) {
                        const int r = iyo - dy;
                        if (r >= 0 && r < 4)
                            acc[r] = __builtin_amdgcn_mfma_f32_32x32x16_bf16(
                                af[dy], bf, acc[r], 0, 0, 0);
                    }
                }
            }
        }
        __syncthreads();

        // ---- epilogue: bias + coalesced full-line stores ----
        const unsigned obase = (unsigned)(b * 64) * HWX + (unsigned)(x0 + n);
        #pragma unroll
        for (int reg = 0; reg < 16; ++reg) {
            const int row = (reg & 3) + 8 * (reg >> 2) + 4 * h;
            const float bb = bias[co0 + row];
            const unsigned cb = obase + (unsigned)(co0 + row) * HWX;
            #pragma unroll
            for (int r = 0; r < 4; ++r) {
                const unsigned Y = (unsigned)(y0 + wrow + r);
                out[cb + Y * 256u] = acc[r][reg] + bb;
            }
        }
    }
}

extern "C" void kernel_launch(void* const* d_in, const int* in_sizes, int n_in,
                              void* d_out, int out_size, void* d_ws, size_t ws_size,
                              hipStream_t stream) {
    const float* x    = (const float*)d_in[0];
    const float* wgt  = (const float*)d_in[1];
    const float* bias = (const float*)d_in[2];
    float* out = (float*)d_out;
    unsigned short* wsA = (unsigned short*)d_ws;   // 73728 B

    prep_weights<<<dim3(144), dim3(256), 0, stream>>>(wgt, wsA);
    conv_mfma<<<dim3(512), dim3(512), 0, stream>>>(x, wsA, bias, out);
}